// Round 9
// baseline (102.204 us; speedup 1.0000x reference)
//
#include <hip/hip_runtime.h>
#include <stdint.h>

#define B_  8
#define C_  512
#define L_  1024
#define NH_ 8
#define HD_ 64

typedef __attribute__((ext_vector_type(8))) short short8;
typedef __attribute__((ext_vector_type(4))) short short4v;
typedef __attribute__((ext_vector_type(4))) float f32x4;
typedef __attribute__((ext_vector_type(2))) unsigned uint2v;

#define MFMA(a,b,c) __builtin_amdgcn_mfma_f32_16x16x32_bf16((a),(b),(c),0,0,0)
#define GLD16(g,l) __builtin_amdgcn_global_load_lds( \
    (const __attribute__((address_space(1))) void*)(g), \
    (__attribute__((address_space(3))) void*)(l), 16, 0, 0)

__device__ __forceinline__ unsigned short f2bf(float f) {
  union { float f; unsigned u; } x; x.f = f;
  unsigned r = x.u + 0x7FFFu + ((x.u >> 16) & 1u);
  return (unsigned short)(r >> 16);
}

// packed f32x2 -> bf16x2 (RNE), gfx950 has no builtin -> inline asm (T12)
__device__ __forceinline__ unsigned cvtpk_bf16(float lo, float hi) {
  unsigned r;
  asm("v_cvt_pk_bf16_f32 %0, %1, %2" : "=v"(r) : "v"(lo), "v"(hi));
  return r;
}

// ---------------- transpose: [B,C,L] f32 -> [B,L,C] bf16 ----------------
__global__ __launch_bounds__(256) void k_transpose(
    const float* __restrict__ q, const float* __restrict__ k,
    unsigned short* __restrict__ qf, unsigned short* __restrict__ kf) {
  __shared__ float t[32][33];
  const int z = blockIdx.z;
  const int b = z >> 1;
  const float* src = (z & 1) ? k : q;
  unsigned short* dst = (z & 1) ? kf : qf;
  const int tx = threadIdx.x & 31;
  const int ty = threadIdx.x >> 5;           // 0..7
  const int l0 = blockIdx.x * 32;
  const int c0 = blockIdx.y * 32;
#pragma unroll
  for (int i = 0; i < 4; ++i)
    t[ty + 8*i][tx] = src[((size_t)b * C_ + c0 + ty + 8*i) * L_ + l0 + tx];
  __syncthreads();
#pragma unroll
  for (int i = 0; i < 4; ++i)
    dst[((size_t)b * L_ + l0 + ty + 8*i) * C_ + c0 + tx] = f2bf(t[tx][ty + 8*i]);
}

// ---------------- weight convert f32 -> bf16 ----------------
__global__ __launch_bounds__(256) void k_convw(
    const float* __restrict__ w0, const float* __restrict__ w1,
    const float* __restrict__ w2, const float* __restrict__ w3,
    unsigned short* __restrict__ dst) {
  const int z = blockIdx.y;
  const float* s = (z == 0) ? w0 : (z == 1) ? w1 : (z == 2) ? w2 : w3;
  unsigned short* d = dst + (size_t)z * (C_ * C_);
  const int i = (blockIdx.x * 256 + threadIdx.x) * 4;
  float4 v = *(const float4*)&s[i];
  short4v p;
  p[0] = (short)f2bf(v.x); p[1] = (short)f2bf(v.y);
  p[2] = (short)f2bf(v.z); p[3] = (short)f2bf(v.w);
  *(short4v*)&d[i] = p;
}

// ---- GEMM core: C[m,n] = sum_k A[m,k]*W[n,k]  (tile (MREP*32) x 128, BK=64) ----
template<int MREP>
__device__ __forceinline__ void gemm_core(
    const unsigned short* __restrict__ A, const unsigned short* __restrict__ W,
    const float* __restrict__ bias, void* __restrict__ outp,
    const float* __restrict__ resQ, const float* __restrict__ resK,
    int mode, float scale, unsigned short* lA, unsigned short* lB,
    int tm, int tn) {
  const int lane = threadIdx.x & 63;
  const int wid  = threadIdx.x >> 6;
  const int wm = wid >> 1, wn = wid & 1;
  const int r16 = lane & 15;
  const int g4  = lane >> 4;

  f32x4 acc[MREP][4];
#pragma unroll
  for (int i = 0; i < MREP; ++i)
#pragma unroll
    for (int j = 0; j < 4; ++j) acc[i][j] = (f32x4){0.f, 0.f, 0.f, 0.f};

  for (int kt = 0; kt < C_; kt += 64) {
#pragma unroll
    for (int i = 0; i < MREP; ++i) {
      int chunk = wid * MREP + i;
      int row = chunk * 8 + (lane >> 3);
      int col = (lane & 7) * 8;
      GLD16(A + (size_t)(tm + row) * C_ + kt + col, &lA[chunk * 512]);
    }
#pragma unroll
    for (int i = 0; i < 4; ++i) {
      int chunk = wid * 4 + i;
      int row = chunk * 8 + (lane >> 3);
      int col = (lane & 7) * 8;
      GLD16(W + (size_t)(tn + row) * C_ + kt + col, &lB[chunk * 512]);
    }
    __syncthreads();
#pragma unroll
    for (int ks = 0; ks < 2; ++ks) {
      const int co = ks * 32 + g4 * 8;
      short8 af[MREP], bw[4];
#pragma unroll
      for (int i = 0; i < MREP; ++i)
        af[i] = *(const short8*)&lA[(wm*(MREP*16) + i*16 + r16) * 64 + co];
#pragma unroll
      for (int j = 0; j < 4; ++j) bw[j] = *(const short8*)&lB[(wn*64 + j*16 + r16) * 64 + co];
#pragma unroll
      for (int i = 0; i < MREP; ++i)
#pragma unroll
        for (int j = 0; j < 4; ++j) acc[i][j] = MFMA(af[i], bw[j], acc[i][j]);
    }
    __syncthreads();
  }

  if (mode <= 1) {
    unsigned short* out = (unsigned short*)outp;
#pragma unroll
    for (int i = 0; i < MREP; ++i)
#pragma unroll
      for (int j = 0; j < 4; ++j) {
        int c = tn + wn*64 + j*16 + r16;
        float bia = bias[c];
        int h = c >> 6, d = c & 63;
#pragma unroll
        for (int r = 0; r < 4; ++r) {
          int gm = tm + wm*(MREP*16) + i*16 + g4*4 + r;
          int b = gm >> 10, l = gm & 1023;
          out[(((size_t)b * NH_ + h) * L_ + l) * HD_ + d] = f2bf((acc[i][j][r] + bia) * scale);
        }
      }
  } else if (mode == 2) {
    unsigned short* out = (unsigned short*)outp;
#pragma unroll
    for (int i = 0; i < MREP; ++i)
#pragma unroll
      for (int j = 0; j < 4; ++j) {
        int c = tn + wn*64 + j*16 + r16;
        float bia = bias[c];
        int h = c >> 6, d = c & 63;
        int gm0 = tm + wm*(MREP*16) + i*16 + g4*4;
        int b = gm0 >> 10, l0 = gm0 & 1023;
        short4v pk;
#pragma unroll
        for (int r = 0; r < 4; ++r) pk[r] = (short)f2bf(acc[i][j][r] + bia);
        *(short4v*)&out[(((size_t)b * NH_ + h) * HD_ + d) * L_ + l0] = pk;
      }
  } else {
    float* out = (float*)outp;
#pragma unroll
    for (int i = 0; i < MREP; ++i)
#pragma unroll
      for (int j = 0; j < 4; ++j) {
        int c = tn + wn*64 + j*16 + r16;
        float bia = bias[c];
        int gm0 = tm + wm*(MREP*16) + i*16 + g4*4;
        int b = gm0 >> 10, l0 = gm0 & 1023;
        size_t idx = ((size_t)b * C_ + c) * L_ + l0;
        float4 q4 = *(const float4*)&resQ[idx];
        float4 k4 = *(const float4*)&resK[idx];
        float4 o4;
        o4.x = acc[i][j][0] + bia + q4.x + k4.x;
        o4.y = acc[i][j][1] + bia + q4.y + k4.y;
        o4.z = acc[i][j][2] + bia + q4.z + k4.z;
        o4.w = acc[i][j][3] + bia + q4.w + k4.w;
        *(float4*)&out[idx] = o4;
      }
  }
}

// 1D grid, 768 blocks. XCD-grouped.
__global__ __launch_bounds__(256) void k_proj(
    const unsigned short* __restrict__ qf, const unsigned short* __restrict__ kf,
    const unsigned short* __restrict__ Wqb, const unsigned short* __restrict__ Wkb,
    const unsigned short* __restrict__ Wvb,
    const float* __restrict__ bq, const float* __restrict__ bk, const float* __restrict__ bv,
    unsigned short* __restrict__ Qw, unsigned short* __restrict__ Kw,
    unsigned short* __restrict__ VTw) {
  __shared__ unsigned short lA[128 * 64];
  __shared__ unsigned short lB[128 * 64];
  const int bid = blockIdx.x;
  const int xcd = bid & 7;
  const int i_  = bid >> 3;            // 0..95
  const int ml  = i_ / 12;             // 0..7
  const int rem = i_ - ml * 12;        // 0..11
  const int z   = rem >> 2;            // 0..2
  const int n   = rem & 3;             // 0..3
  const int m   = xcd * 8 + ml;        // 0..63
  const unsigned short* A = (z == 0) ? qf : kf;
  const unsigned short* W = (z == 0) ? Wqb : (z == 1) ? Wkb : Wvb;
  const float* bias = (z == 0) ? bq : (z == 1) ? bk : bv;
  void* out = (z == 0) ? (void*)Qw : (z == 1) ? (void*)Kw : (void*)VTw;
  // Q scale folds head-dim scaling AND log2(e) so attn softmax runs in exp2 domain.
  float scale = (z == 0) ? 0.125f * 1.44269504088896f : 1.0f;
  gemm_core<4>(A, W, bias, out, nullptr, nullptr, z, scale, lA, lB, m * 128, n * 128);
}

// 1D grid, 512 blocks (64x128 tile -> 2 blocks/CU for latency hiding).
__global__ __launch_bounds__(256) void k_outproj(
    const unsigned short* __restrict__ O, const unsigned short* __restrict__ Wob,
    const float* __restrict__ bo, float* __restrict__ out,
    const float* __restrict__ query, const float* __restrict__ key) {
  __shared__ unsigned short lA[64 * 64];
  __shared__ unsigned short lB[128 * 64];
  const int bid = blockIdx.x;
  const int xcd = bid & 7;
  const int i_  = bid >> 3;             // 0..63
  const int m   = xcd * 16 + (i_ >> 2); // 0..127
  const int n   = i_ & 3;
  gemm_core<2>(O, Wob, bo, out, query, key, 3, 1.0f, lA, lB, m * 64, n * 128);
}

// ---------------- flash attention ----------------
// Q,K: [B,NH,L,64] bf16 (Q pre-scaled by 0.125*log2e), VT: [B,NH,64,L] bf16.
// 512 blocks (64 bh x 8 q-blocks of 128); 4 waves, 32 q-rows/wave.
// 32 rows/wave halves per-unit-work LDS-read traffic (each wave reads the
// full K/V tile regardless of row count -> amortize over 2x rows).
// SWAPPED QK^T (lane owns q-rows r16 and 16+r16). STATIC-MAX softmax:
// p = exp2(s) directly (|s| <= ~18 << 127 overflow). l on MFMA pipe.
__global__ __launch_bounds__(256, 2) void k_attn(
    const unsigned short* __restrict__ Q, const unsigned short* __restrict__ K,
    const unsigned short* __restrict__ VT, unsigned short* __restrict__ O) {
  __shared__ unsigned short Kt[2][64 * 64];
  __shared__ unsigned short Vt[2][64 * 64];
  __shared__ __align__(16) unsigned short Pl[4][32 * 36];
  const int lane = threadIdx.x & 63;
  const int wid  = threadIdx.x >> 6;
  const int bid  = blockIdx.x;
  const int xcd  = bid & 7;
  const int i_   = bid >> 3;                   // 0..63
  const int bh   = xcd * 8 + (i_ >> 3);        // 0..63, 8 heads per XCD
  const int qb   = i_ & 7;                     // 0..7
  const int qrow0 = qb * 128 + wid * 32;
  const int r16 = lane & 15;
  const int g4  = lane >> 4;
  const size_t base = (size_t)bh * L_ * HD_;
  const unsigned short* Kg = K + base;
  const unsigned short* Vg = VT + base;        // [64 d][1024 l]

  // staging geometry: tile = 64x64 bf16 = 512 slots of 16B; wave stages 128 slots
  const int s0 = wid * 128 + lane;             // slot for i2=0 (i2=1 adds 64)
  const int row0 = s0 >> 3,        ch0 = (s0 & 7) ^ (row0 & 7);
  const int row1 = (s0 + 64) >> 3, ch1 = ((s0 + 64) & 7) ^ (row1 & 7);

#define STAGE_KV(nxt, kt0) { \
    GLD16(Kg + (size_t)((kt0) + row0) * HD_ + ch0 * 8, &Kt[nxt][(wid*128)*8]); \
    GLD16(Kg + (size_t)((kt0) + row1) * HD_ + ch1 * 8, &Kt[nxt][(wid*128+64)*8]); \
    GLD16(Vg + (size_t)row0 * L_ + (kt0) + ch0 * 8, &Vt[nxt][(wid*128)*8]); \
    GLD16(Vg + (size_t)row1 * L_ + (kt0) + ch1 * 8, &Vt[nxt][(wid*128+64)*8]); \
  }

  short8 qv[2][2];
#pragma unroll
  for (int i = 0; i < 2; ++i)
#pragma unroll
    for (int ks = 0; ks < 2; ++ks)
      qv[i][ks] = *(const short8*)(Q + base + (size_t)(qrow0 + i*16 + r16) * HD_ + ks*32 + g4*8);

  short8 vones;
#pragma unroll
  for (int e = 0; e < 8; ++e) vones[e] = (short)0x3F80;   // bf16 1.0

  f32x4 lacc[2];
  f32x4 oacc[2][4];
#pragma unroll
  for (int i = 0; i < 2; ++i) {
    lacc[i] = (f32x4){0.f, 0.f, 0.f, 0.f};
#pragma unroll
    for (int j = 0; j < 4; ++j) oacc[i][j] = (f32x4){0.f, 0.f, 0.f, 0.f};
  }

  unsigned short* myP = &Pl[wid][0];

  STAGE_KV(0, 0);
  __syncthreads();

  int cur = 0;
  for (int t = 0; t < 16; ++t) {
    if (t < 15) STAGE_KV(cur ^ 1, (t + 1) * 64);

    const unsigned short* lK = &Kt[cur][0];
    const unsigned short* lV = &Vt[cur][0];

    f32x4 sc[2][4];
#pragma unroll
    for (int i = 0; i < 2; ++i)
#pragma unroll
      for (int cf = 0; cf < 4; ++cf) sc[i][cf] = (f32x4){0.f, 0.f, 0.f, 0.f};

    const int swz = r16 & 7;
    __builtin_amdgcn_s_setprio(1);
#pragma unroll
    for (int cf = 0; cf < 4; ++cf) {
      const int rowb = (cf*16 + r16) * 64;
      short8 kb0 = *(const short8*)&lK[rowb + ((g4) ^ swz) * 8];
      short8 kb1 = *(const short8*)&lK[rowb + ((4 + g4) ^ swz) * 8];
      sc[0][cf] = MFMA(kb0, qv[0][0], sc[0][cf]);   // swapped: S^T[k, q]
      sc[0][cf] = MFMA(kb1, qv[0][1], sc[0][cf]);
      sc[1][cf] = MFMA(kb0, qv[1][0], sc[1][cf]);
      sc[1][cf] = MFMA(kb1, qv[1][1], sc[1][cf]);
    }
    __builtin_amdgcn_s_setprio(0);

    // PV in two 32-k halves; p = exp2(s) (static max), pack via cvt_pk,
    // l via MFMA(pa, ones) on the matrix pipe.
#pragma unroll
    for (int half = 0; half < 2; ++half) {
#pragma unroll
      for (int i = 0; i < 2; ++i)
#pragma unroll
        for (int cfl = 0; cfl < 2; ++cfl) {
          const int cf = half * 2 + cfl;
          float p0 = exp2f(sc[i][cf][0]);
          float p1 = exp2f(sc[i][cf][1]);
          float p2 = exp2f(sc[i][cf][2]);
          float p3 = exp2f(sc[i][cf][3]);
          uint2v pk;
          pk[0] = cvtpk_bf16(p0, p1);
          pk[1] = cvtpk_bf16(p2, p3);
          *(uint2v*)&myP[(i*16 + r16) * 36 + cfl * 16 + g4 * 4] = pk;
        }
      short8 pa0 = *(const short8*)&myP[r16 * 36 + g4 * 8];
      short8 pa1 = *(const short8*)&myP[(16 + r16) * 36 + g4 * 8];
      __builtin_amdgcn_s_setprio(1);
      lacc[0] = MFMA(pa0, vones, lacc[0]);
      lacc[1] = MFMA(pa1, vones, lacc[1]);
#pragma unroll
      for (int j = 0; j < 4; ++j) {
        short8 vb = *(const short8*)&lV[(j*16 + r16) * 64 + ((half*4 + g4) ^ swz) * 8];
        oacc[0][j] = MFMA(pa0, vb, oacc[0][j]);
        oacc[1][j] = MFMA(pa1, vb, oacc[1][j]);
      }
      __builtin_amdgcn_s_setprio(0);
    }

    __syncthreads();
    cur ^= 1;
  }

  const int b = bh >> 3, h = bh & 7;
#pragma unroll
  for (int i = 0; i < 2; ++i) {
    float linv[4];
#pragma unroll
    for (int r = 0; r < 4; ++r) linv[r] = 1.0f / lacc[i][r];
#pragma unroll
    for (int j = 0; j < 4; ++j)
#pragma unroll
      for (int r = 0; r < 4; ++r) {
        int row = qrow0 + i*16 + g4*4 + r;
        int col = h*64 + j*16 + r16;
        O[((size_t)b * L_ + row) * C_ + col] = f2bf(oacc[i][j][r] * linv[r]);
      }
  }
#undef STAGE_KV
}

extern "C" void kernel_launch(void* const* d_in, const int* in_sizes, int n_in,
                              void* d_out, int out_size, void* d_ws, size_t ws_size,
                              hipStream_t stream) {
  (void)in_sizes; (void)n_in; (void)out_size; (void)ws_size;
  const float* query = (const float*)d_in[0];
  const float* key   = (const float*)d_in[1];
  const float* Wq = (const float*)d_in[2];
  const float* bq = (const float*)d_in[3];
  const float* Wk = (const float*)d_in[4];
  const float* bk = (const float*)d_in[5];
  const float* Wv = (const float*)d_in[6];
  const float* bv = (const float*)d_in[7];
  const float* Wo = (const float*)d_in[8];
  const float* bo = (const float*)d_in[9];

  char* ws = (char*)d_ws;
  unsigned short* qf  = (unsigned short*)(ws);                  // 8 MB
  unsigned short* kf  = (unsigned short*)(ws + 8388608);        // 8 MB
  unsigned short* Wqb = (unsigned short*)(ws + 16777216);       // 4x 512KB
  unsigned short* Wkb = Wqb + 262144;
  unsigned short* Wvb = Wkb + 262144;
  unsigned short* Wob = Wvb + 262144;
  unsigned short* Qw  = (unsigned short*)(ws + 18874368);       // 8 MB
  unsigned short* Kw  = (unsigned short*)(ws + 27262976);       // 8 MB
  unsigned short* VTw = (unsigned short*)(ws + 35651584);       // 8 MB
  unsigned short* Ow  = (unsigned short*)(ws + 44040192);       // 8 MB

  k_transpose<<<dim3(32, 16, 16), 256, 0, stream>>>(query, key, qf, kf);
  k_convw<<<dim3(256, 4), 256, 0, stream>>>(Wq, Wk, Wv, Wo, Wqb);
  k_proj<<<dim3(768), 256, 0, stream>>>(qf, kf, Wqb, Wkb, Wvb, bq, bk, bv, Qw, Kw, VTw);
  k_attn<<<dim3(512), 256, 0, stream>>>(Qw, Kw, VTw, Ow);
  k_outproj<<<dim3(512), 256, 0, stream>>>(Ow, Wob, bo, (float*)d_out, query, key);
}

// Round 10
// 94.865 us; speedup vs baseline: 1.0774x; 1.0774x over previous
//
#include <hip/hip_runtime.h>
#include <stdint.h>

#define B_  8
#define C_  512
#define L_  1024
#define NH_ 8
#define HD_ 64

typedef __attribute__((ext_vector_type(8))) short short8;
typedef __attribute__((ext_vector_type(4))) short short4v;
typedef __attribute__((ext_vector_type(4))) float f32x4;
typedef __attribute__((ext_vector_type(2))) unsigned uint2v;

#define MFMA(a,b,c) __builtin_amdgcn_mfma_f32_16x16x32_bf16((a),(b),(c),0,0,0)
#define GLD16(g,l) __builtin_amdgcn_global_load_lds( \
    (const __attribute__((address_space(1))) void*)(g), \
    (__attribute__((address_space(3))) void*)(l), 16, 0, 0)

__device__ __forceinline__ unsigned short f2bf(float f) {
  union { float f; unsigned u; } x; x.f = f;
  unsigned r = x.u + 0x7FFFu + ((x.u >> 16) & 1u);
  return (unsigned short)(r >> 16);
}

// packed f32x2 -> bf16x2 (RNE), gfx950 has no builtin -> inline asm (T12)
__device__ __forceinline__ unsigned cvtpk_bf16(float lo, float hi) {
  unsigned r;
  asm("v_cvt_pk_bf16_f32 %0, %1, %2" : "=v"(r) : "v"(lo), "v"(hi));
  return r;
}

// ---------------- transpose: [B,C,L] f32 -> [B,L,C] bf16 ----------------
__global__ __launch_bounds__(256) void k_transpose(
    const float* __restrict__ q, const float* __restrict__ k,
    unsigned short* __restrict__ qf, unsigned short* __restrict__ kf) {
  __shared__ float t[32][33];
  const int z = blockIdx.z;
  const int b = z >> 1;
  const float* src = (z & 1) ? k : q;
  unsigned short* dst = (z & 1) ? kf : qf;
  const int tx = threadIdx.x & 31;
  const int ty = threadIdx.x >> 5;           // 0..7
  const int l0 = blockIdx.x * 32;
  const int c0 = blockIdx.y * 32;
#pragma unroll
  for (int i = 0; i < 4; ++i)
    t[ty + 8*i][tx] = src[((size_t)b * C_ + c0 + ty + 8*i) * L_ + l0 + tx];
  __syncthreads();
#pragma unroll
  for (int i = 0; i < 4; ++i)
    dst[((size_t)b * L_ + l0 + ty + 8*i) * C_ + c0 + tx] = f2bf(t[tx][ty + 8*i]);
}

// ---------------- weight convert f32 -> bf16 ----------------
__global__ __launch_bounds__(256) void k_convw(
    const float* __restrict__ w0, const float* __restrict__ w1,
    const float* __restrict__ w2, const float* __restrict__ w3,
    unsigned short* __restrict__ dst) {
  const int z = blockIdx.y;
  const float* s = (z == 0) ? w0 : (z == 1) ? w1 : (z == 2) ? w2 : w3;
  unsigned short* d = dst + (size_t)z * (C_ * C_);
  const int i = (blockIdx.x * 256 + threadIdx.x) * 4;
  float4 v = *(const float4*)&s[i];
  short4v p;
  p[0] = (short)f2bf(v.x); p[1] = (short)f2bf(v.y);
  p[2] = (short)f2bf(v.z); p[3] = (short)f2bf(v.w);
  *(short4v*)&d[i] = p;
}

// ---- GEMM core: C[m,n] = sum_k A[m,k]*W[n,k]  (tile (MREP*32) x 128, BK=64) ----
template<int MREP>
__device__ __forceinline__ void gemm_core(
    const unsigned short* __restrict__ A, const unsigned short* __restrict__ W,
    const float* __restrict__ bias, void* __restrict__ outp,
    const float* __restrict__ resQ, const float* __restrict__ resK,
    int mode, float scale, unsigned short* lA, unsigned short* lB,
    int tm, int tn) {
  const int lane = threadIdx.x & 63;
  const int wid  = threadIdx.x >> 6;
  const int wm = wid >> 1, wn = wid & 1;
  const int r16 = lane & 15;
  const int g4  = lane >> 4;

  f32x4 acc[MREP][4];
#pragma unroll
  for (int i = 0; i < MREP; ++i)
#pragma unroll
    for (int j = 0; j < 4; ++j) acc[i][j] = (f32x4){0.f, 0.f, 0.f, 0.f};

  for (int kt = 0; kt < C_; kt += 64) {
#pragma unroll
    for (int i = 0; i < MREP; ++i) {
      int chunk = wid * MREP + i;
      int row = chunk * 8 + (lane >> 3);
      int col = (lane & 7) * 8;
      GLD16(A + (size_t)(tm + row) * C_ + kt + col, &lA[chunk * 512]);
    }
#pragma unroll
    for (int i = 0; i < 4; ++i) {
      int chunk = wid * 4 + i;
      int row = chunk * 8 + (lane >> 3);
      int col = (lane & 7) * 8;
      GLD16(W + (size_t)(tn + row) * C_ + kt + col, &lB[chunk * 512]);
    }
    __syncthreads();
#pragma unroll
    for (int ks = 0; ks < 2; ++ks) {
      const int co = ks * 32 + g4 * 8;
      short8 af[MREP], bw[4];
#pragma unroll
      for (int i = 0; i < MREP; ++i)
        af[i] = *(const short8*)&lA[(wm*(MREP*16) + i*16 + r16) * 64 + co];
#pragma unroll
      for (int j = 0; j < 4; ++j) bw[j] = *(const short8*)&lB[(wn*64 + j*16 + r16) * 64 + co];
#pragma unroll
      for (int i = 0; i < MREP; ++i)
#pragma unroll
        for (int j = 0; j < 4; ++j) acc[i][j] = MFMA(af[i], bw[j], acc[i][j]);
    }
    __syncthreads();
  }

  if (mode <= 1) {
    unsigned short* out = (unsigned short*)outp;
#pragma unroll
    for (int i = 0; i < MREP; ++i)
#pragma unroll
      for (int j = 0; j < 4; ++j) {
        int c = tn + wn*64 + j*16 + r16;
        float bia = bias[c];
        int h = c >> 6, d = c & 63;
#pragma unroll
        for (int r = 0; r < 4; ++r) {
          int gm = tm + wm*(MREP*16) + i*16 + g4*4 + r;
          int b = gm >> 10, l = gm & 1023;
          out[(((size_t)b * NH_ + h) * L_ + l) * HD_ + d] = f2bf((acc[i][j][r] + bia) * scale);
        }
      }
  } else if (mode == 2) {
    unsigned short* out = (unsigned short*)outp;
#pragma unroll
    for (int i = 0; i < MREP; ++i)
#pragma unroll
      for (int j = 0; j < 4; ++j) {
        int c = tn + wn*64 + j*16 + r16;
        float bia = bias[c];
        int h = c >> 6, d = c & 63;
        int gm0 = tm + wm*(MREP*16) + i*16 + g4*4;
        int b = gm0 >> 10, l0 = gm0 & 1023;
        short4v pk;
#pragma unroll
        for (int r = 0; r < 4; ++r) pk[r] = (short)f2bf(acc[i][j][r] + bia);
        *(short4v*)&out[(((size_t)b * NH_ + h) * HD_ + d) * L_ + l0] = pk;
      }
  } else {
    float* out = (float*)outp;
#pragma unroll
    for (int i = 0; i < MREP; ++i)
#pragma unroll
      for (int j = 0; j < 4; ++j) {
        int c = tn + wn*64 + j*16 + r16;
        float bia = bias[c];
        int gm0 = tm + wm*(MREP*16) + i*16 + g4*4;
        int b = gm0 >> 10, l0 = gm0 & 1023;
        size_t idx = ((size_t)b * C_ + c) * L_ + l0;
        float4 q4 = *(const float4*)&resQ[idx];
        float4 k4 = *(const float4*)&resK[idx];
        float4 o4;
        o4.x = acc[i][j][0] + bia + q4.x + k4.x;
        o4.y = acc[i][j][1] + bia + q4.y + k4.y;
        o4.z = acc[i][j][2] + bia + q4.z + k4.z;
        o4.w = acc[i][j][3] + bia + q4.w + k4.w;
        *(float4*)&out[idx] = o4;
      }
  }
}

// 1D grid, 768 blocks. XCD-grouped.
__global__ __launch_bounds__(256) void k_proj(
    const unsigned short* __restrict__ qf, const unsigned short* __restrict__ kf,
    const unsigned short* __restrict__ Wqb, const unsigned short* __restrict__ Wkb,
    const unsigned short* __restrict__ Wvb,
    const float* __restrict__ bq, const float* __restrict__ bk, const float* __restrict__ bv,
    unsigned short* __restrict__ Qw, unsigned short* __restrict__ Kw,
    unsigned short* __restrict__ VTw) {
  __shared__ unsigned short lA[128 * 64];
  __shared__ unsigned short lB[128 * 64];
  const int bid = blockIdx.x;
  const int xcd = bid & 7;
  const int i_  = bid >> 3;            // 0..95
  const int ml  = i_ / 12;             // 0..7
  const int rem = i_ - ml * 12;        // 0..11
  const int z   = rem >> 2;            // 0..2
  const int n   = rem & 3;             // 0..3
  const int m   = xcd * 8 + ml;        // 0..63
  const unsigned short* A = (z == 0) ? qf : kf;
  const unsigned short* W = (z == 0) ? Wqb : (z == 1) ? Wkb : Wvb;
  const float* bias = (z == 0) ? bq : (z == 1) ? bk : bv;
  void* out = (z == 0) ? (void*)Qw : (z == 1) ? (void*)Kw : (void*)VTw;
  // Q scale folds head-dim scaling AND log2(e) so attn softmax runs in exp2 domain.
  float scale = (z == 0) ? 0.125f * 1.44269504088896f : 1.0f;
  gemm_core<4>(A, W, bias, out, nullptr, nullptr, z, scale, lA, lB, m * 128, n * 128);
}

// 1D grid, 512 blocks (64x128 tile -> 2 blocks/CU for latency hiding).
__global__ __launch_bounds__(256) void k_outproj(
    const unsigned short* __restrict__ O, const unsigned short* __restrict__ Wob,
    const float* __restrict__ bo, float* __restrict__ out,
    const float* __restrict__ query, const float* __restrict__ key) {
  __shared__ unsigned short lA[64 * 64];
  __shared__ unsigned short lB[128 * 64];
  const int bid = blockIdx.x;
  const int xcd = bid & 7;
  const int i_  = bid >> 3;             // 0..63
  const int m   = xcd * 16 + (i_ >> 2); // 0..127
  const int n   = i_ & 3;
  gemm_core<2>(O, Wob, bo, out, query, key, 3, 1.0f, lA, lB, m * 64, n * 128);
}

// ---------------- flash attention ----------------
// Q,K: [B,NH,L,64] bf16 (Q pre-scaled by 0.125*log2e), VT: [B,NH,64,L] bf16.
// 1024 blocks (64 bh x 16 q-blocks of 64); 4 waves, 16 q-rows/wave.
// SWAPPED QK^T with PERMUTED K-rows so the output IS the PV A-fragment:
// MFMA (h,c) loads K-row pi = h*32 + (r16>>2)*8 + (r16&3)*2 + c; output slot
// (h,c,g4,r) then holds key k = h*32 + g4*8 + 2r + c -> exp2 + cvt_pk pack
// the PV A-operand entirely in registers (NO P LDS round-trip, no Pl buffer).
// STATIC-MAX softmax (|s|<=~18 << 127). l accumulated on MFMA pipe via ones.
__global__ __launch_bounds__(256, 4) void k_attn(
    const unsigned short* __restrict__ Q, const unsigned short* __restrict__ K,
    const unsigned short* __restrict__ VT, unsigned short* __restrict__ O) {
  __shared__ unsigned short Kt[2][64 * 64];
  __shared__ unsigned short Vt[2][64 * 64];
  const int lane = threadIdx.x & 63;
  const int wid  = threadIdx.x >> 6;
  const int bid  = blockIdx.x;
  const int xcd  = bid & 7;
  const int i_   = bid >> 3;                   // 0..127
  const int bh   = xcd * 8 + (i_ >> 4);        // 0..63, 8 heads per XCD
  const int qb   = i_ & 15;                    // 0..15
  const int qrow0 = qb * 64 + wid * 16;
  const int r16 = lane & 15;
  const int g4  = lane >> 4;
  const size_t base = (size_t)bh * L_ * HD_;
  const unsigned short* Kg = K + base;
  const unsigned short* Vg = VT + base;        // [64 d][1024 l]

  // staging geometry: tile = 64x64 bf16 = 512 slots of 16B; wave stages 128 slots
  const int s0 = wid * 128 + lane;             // slot for i2=0 (i2=1 adds 64)
  const int row0 = s0 >> 3,        ch0 = (s0 & 7) ^ (row0 & 7);
  const int row1 = (s0 + 64) >> 3, ch1 = ((s0 + 64) & 7) ^ (row1 & 7);

#define STAGE_KV(nxt, kt0) { \
    GLD16(Kg + (size_t)((kt0) + row0) * HD_ + ch0 * 8, &Kt[nxt][(wid*128)*8]); \
    GLD16(Kg + (size_t)((kt0) + row1) * HD_ + ch1 * 8, &Kt[nxt][(wid*128+64)*8]); \
    GLD16(Vg + (size_t)row0 * L_ + (kt0) + ch0 * 8, &Vt[nxt][(wid*128)*8]); \
    GLD16(Vg + (size_t)row1 * L_ + (kt0) + ch1 * 8, &Vt[nxt][(wid*128+64)*8]); \
  }

  short8 qv[2];
#pragma unroll
  for (int ks = 0; ks < 2; ++ks)
    qv[ks] = *(const short8*)(Q + base + (size_t)(qrow0 + r16) * HD_ + ks*32 + g4*8);

  short8 vones;
#pragma unroll
  for (int e = 0; e < 8; ++e) vones[e] = (short)0x3F80;   // bf16 1.0

  f32x4 lacc = (f32x4){0.f, 0.f, 0.f, 0.f};
  f32x4 oacc[4];
#pragma unroll
  for (int j = 0; j < 4; ++j) oacc[j] = (f32x4){0.f, 0.f, 0.f, 0.f};

  STAGE_KV(0, 0);
  __syncthreads();

  int cur = 0;
  for (int t = 0; t < 16; ++t) {
    if (t < 15) STAGE_KV(cur ^ 1, (t + 1) * 64);

    const unsigned short* lK = &Kt[cur][0];
    const unsigned short* lV = &Vt[cur][0];

    f32x4 sc[4];
#pragma unroll
    for (int cf = 0; cf < 4; ++cf) sc[cf] = (f32x4){0.f, 0.f, 0.f, 0.f};

    __builtin_amdgcn_s_setprio(1);
#pragma unroll
    for (int cf = 0; cf < 4; ++cf) {
      const int h = cf >> 1, c = cf & 1;
      // permuted K-row: A-row r16 <- key row h*32 + (r16>>2)*8 + (r16&3)*2 + c
      const int rr = h*32 + ((r16 >> 2) << 3) + ((r16 & 3) << 1) + c;
      const int s  = ((r16 & 3) << 1) + c;            // rr & 7
      const int rowb = rr * 64;
      short8 kb0 = *(const short8*)&lK[rowb + ((g4) ^ s) * 8];
      short8 kb1 = *(const short8*)&lK[rowb + ((4 + g4) ^ s) * 8];
      sc[cf] = MFMA(kb0, qv[0], sc[cf]);   // swapped: S^T[k, q]
      sc[cf] = MFMA(kb1, qv[1], sc[cf]);
    }
    __builtin_amdgcn_s_setprio(0);

    // p = exp2(s) (static max), pack PV A-fragment in registers:
    // half h word r = cvtpk(p[h,c=0][r], p[h,c=1][r]) -> elements e=2r+c,
    // i.e. k = g4*8 + e  ✓ matches A-frag layout.
    const int swz = r16 & 7;
#pragma unroll
    for (int h = 0; h < 2; ++h) {
      union { unsigned u[4]; short8 s8; } pu;
#pragma unroll
      for (int r = 0; r < 4; ++r)
        pu.u[r] = cvtpk_bf16(exp2f(sc[h*2][r]), exp2f(sc[h*2+1][r]));
      short8 pa = pu.s8;
      __builtin_amdgcn_s_setprio(1);
      lacc = MFMA(pa, vones, lacc);
#pragma unroll
      for (int j = 0; j < 4; ++j) {
        short8 vb = *(const short8*)&lV[(j*16 + r16) * 64 + ((h*4 + g4) ^ swz) * 8];
        oacc[j] = MFMA(pa, vb, oacc[j]);
      }
      __builtin_amdgcn_s_setprio(0);
    }

    __syncthreads();
    cur ^= 1;
  }

  const int b = bh >> 3, h = bh & 7;
  float linv[4];
#pragma unroll
  for (int r = 0; r < 4; ++r) linv[r] = 1.0f / lacc[r];
#pragma unroll
  for (int j = 0; j < 4; ++j)
#pragma unroll
    for (int r = 0; r < 4; ++r) {
      int row = qrow0 + g4*4 + r;
      int col = h*64 + j*16 + r16;
      O[((size_t)b * L_ + row) * C_ + col] = f2bf(oacc[j][r] * linv[r]);
    }
#undef STAGE_KV
}

extern "C" void kernel_launch(void* const* d_in, const int* in_sizes, int n_in,
                              void* d_out, int out_size, void* d_ws, size_t ws_size,
                              hipStream_t stream) {
  (void)in_sizes; (void)n_in; (void)out_size; (void)ws_size;
  const float* query = (const float*)d_in[0];
  const float* key   = (const float*)d_in[1];
  const float* Wq = (const float*)d_in[2];
  const float* bq = (const float*)d_in[3];
  const float* Wk = (const float*)d_in[4];
  const float* bk = (const float*)d_in[5];
  const float* Wv = (const float*)d_in[6];
  const float* bv = (const float*)d_in[7];
  const float* Wo = (const float*)d_in[8];
  const float* bo = (const float*)d_in[9];

  char* ws = (char*)d_ws;
  unsigned short* qf  = (unsigned short*)(ws);                  // 8 MB
  unsigned short* kf  = (unsigned short*)(ws + 8388608);        // 8 MB
  unsigned short* Wqb = (unsigned short*)(ws + 16777216);       // 4x 512KB
  unsigned short* Wkb = Wqb + 262144;
  unsigned short* Wvb = Wkb + 262144;
  unsigned short* Wob = Wvb + 262144;
  unsigned short* Qw  = (unsigned short*)(ws + 18874368);       // 8 MB
  unsigned short* Kw  = (unsigned short*)(ws + 27262976);       // 8 MB
  unsigned short* VTw = (unsigned short*)(ws + 35651584);       // 8 MB
  unsigned short* Ow  = (unsigned short*)(ws + 44040192);       // 8 MB

  k_transpose<<<dim3(32, 16, 16), 256, 0, stream>>>(query, key, qf, kf);
  k_convw<<<dim3(256, 4), 256, 0, stream>>>(Wq, Wk, Wv, Wo, Wqb);
  k_proj<<<dim3(768), 256, 0, stream>>>(qf, kf, Wqb, Wkb, Wvb, bq, bk, bv, Qw, Kw, VTw);
  k_attn<<<dim3(1024), 256, 0, stream>>>(Qw, Kw, VTw, Ow);
  k_outproj<<<dim3(512), 256, 0, stream>>>(Ow, Wob, bo, (float*)d_out, query, key);
}

// Round 11
// 93.035 us; speedup vs baseline: 1.0985x; 1.0197x over previous
//
#include <hip/hip_runtime.h>
#include <stdint.h>

#define B_  8
#define C_  512
#define L_  1024
#define NH_ 8
#define HD_ 64

typedef __attribute__((ext_vector_type(8))) short short8;
typedef __attribute__((ext_vector_type(4))) short short4v;
typedef __attribute__((ext_vector_type(4))) float f32x4;
typedef __attribute__((ext_vector_type(2))) unsigned uint2v;

#define MFMA(a,b,c) __builtin_amdgcn_mfma_f32_16x16x32_bf16((a),(b),(c),0,0,0)
#define GLD16(g,l) __builtin_amdgcn_global_load_lds( \
    (const __attribute__((address_space(1))) void*)(g), \
    (__attribute__((address_space(3))) void*)(l), 16, 0, 0)

__device__ __forceinline__ unsigned short f2bf(float f) {
  union { float f; unsigned u; } x; x.f = f;
  unsigned r = x.u + 0x7FFFu + ((x.u >> 16) & 1u);
  return (unsigned short)(r >> 16);
}

// packed f32x2 -> bf16x2 (RNE), gfx950 has no builtin -> inline asm (T12)
__device__ __forceinline__ unsigned cvtpk_bf16(float lo, float hi) {
  unsigned r;
  asm("v_cvt_pk_bf16_f32 %0, %1, %2" : "=v"(r) : "v"(lo), "v"(hi));
  return r;
}

// -------- transpose [B,C,L] f32 -> [B,L,C] bf16  (z=0..15) + weight convert (z=16) ----
__global__ __launch_bounds__(256) void k_transpose(
    const float* __restrict__ q, const float* __restrict__ k,
    unsigned short* __restrict__ qf, unsigned short* __restrict__ kf,
    const float* __restrict__ w0, const float* __restrict__ w1,
    const float* __restrict__ w2, const float* __restrict__ w3,
    unsigned short* __restrict__ wdst) {
  const int z = blockIdx.z;
  if (z == 16) {
    // weight convert: 512 block-slots x 2048 f32 each over [Wq|Wk|Wv|Wo]
    const int gb = blockIdx.y * 32 + blockIdx.x;          // 0..511
    const float* s = (gb < 128) ? w0 : (gb < 256) ? w1 : (gb < 384) ? w2 : w3;
    const int off = (gb & 127) * 2048 + threadIdx.x * 8;
    float4 v0 = *(const float4*)&s[off];
    float4 v1 = *(const float4*)&s[off + 4];
    short8 p;
    p[0] = (short)f2bf(v0.x); p[1] = (short)f2bf(v0.y);
    p[2] = (short)f2bf(v0.z); p[3] = (short)f2bf(v0.w);
    p[4] = (short)f2bf(v1.x); p[5] = (short)f2bf(v1.y);
    p[6] = (short)f2bf(v1.z); p[7] = (short)f2bf(v1.w);
    *(short8*)&wdst[(size_t)(gb >> 7) * 262144 + off] = p;
    return;
  }
  __shared__ float t[32][33];
  const int b = z >> 1;
  const float* src = (z & 1) ? k : q;
  unsigned short* dst = (z & 1) ? kf : qf;
  const int tx = threadIdx.x & 31;
  const int ty = threadIdx.x >> 5;           // 0..7
  const int l0 = blockIdx.x * 32;
  const int c0 = blockIdx.y * 32;
#pragma unroll
  for (int i = 0; i < 4; ++i)
    t[ty + 8*i][tx] = src[((size_t)b * C_ + c0 + ty + 8*i) * L_ + l0 + tx];
  __syncthreads();
#pragma unroll
  for (int i = 0; i < 4; ++i)
    dst[((size_t)b * L_ + l0 + ty + 8*i) * C_ + c0 + tx] = f2bf(t[tx][ty + 8*i]);
}

// ---- GEMM core: C[m,n] = sum_k A[m,k]*W[n,k]  (tile (MREP*32) x 128, BK=64) ----
template<int MREP>
__device__ __forceinline__ void gemm_core(
    const unsigned short* __restrict__ A, const unsigned short* __restrict__ W,
    const float* __restrict__ bias, void* __restrict__ outp,
    const float* __restrict__ resQ, const float* __restrict__ resK,
    int mode, float scale, unsigned short* lA, unsigned short* lB,
    int tm, int tn) {
  const int lane = threadIdx.x & 63;
  const int wid  = threadIdx.x >> 6;
  const int wm = wid >> 1, wn = wid & 1;
  const int r16 = lane & 15;
  const int g4  = lane >> 4;

  f32x4 acc[MREP][4];
#pragma unroll
  for (int i = 0; i < MREP; ++i)
#pragma unroll
    for (int j = 0; j < 4; ++j) acc[i][j] = (f32x4){0.f, 0.f, 0.f, 0.f};

  for (int kt = 0; kt < C_; kt += 64) {
#pragma unroll
    for (int i = 0; i < MREP; ++i) {
      int chunk = wid * MREP + i;
      int row = chunk * 8 + (lane >> 3);
      int col = (lane & 7) * 8;
      GLD16(A + (size_t)(tm + row) * C_ + kt + col, &lA[chunk * 512]);
    }
#pragma unroll
    for (int i = 0; i < 4; ++i) {
      int chunk = wid * 4 + i;
      int row = chunk * 8 + (lane >> 3);
      int col = (lane & 7) * 8;
      GLD16(W + (size_t)(tn + row) * C_ + kt + col, &lB[chunk * 512]);
    }
    __syncthreads();
#pragma unroll
    for (int ks = 0; ks < 2; ++ks) {
      const int co = ks * 32 + g4 * 8;
      short8 af[MREP], bw[4];
#pragma unroll
      for (int i = 0; i < MREP; ++i)
        af[i] = *(const short8*)&lA[(wm*(MREP*16) + i*16 + r16) * 64 + co];
#pragma unroll
      for (int j = 0; j < 4; ++j) bw[j] = *(const short8*)&lB[(wn*64 + j*16 + r16) * 64 + co];
#pragma unroll
      for (int i = 0; i < MREP; ++i)
#pragma unroll
        for (int j = 0; j < 4; ++j) acc[i][j] = MFMA(af[i], bw[j], acc[i][j]);
    }
    __syncthreads();
  }

  if (mode <= 1) {
    unsigned short* out = (unsigned short*)outp;
#pragma unroll
    for (int i = 0; i < MREP; ++i)
#pragma unroll
      for (int j = 0; j < 4; ++j) {
        int c = tn + wn*64 + j*16 + r16;
        float bia = bias[c];
        int h = c >> 6, d = c & 63;
#pragma unroll
        for (int r = 0; r < 4; ++r) {
          int gm = tm + wm*(MREP*16) + i*16 + g4*4 + r;
          int b = gm >> 10, l = gm & 1023;
          out[(((size_t)b * NH_ + h) * L_ + l) * HD_ + d] = f2bf((acc[i][j][r] + bia) * scale);
        }
      }
  } else if (mode == 2) {
    unsigned short* out = (unsigned short*)outp;
#pragma unroll
    for (int i = 0; i < MREP; ++i)
#pragma unroll
      for (int j = 0; j < 4; ++j) {
        int c = tn + wn*64 + j*16 + r16;
        float bia = bias[c];
        int h = c >> 6, d = c & 63;
        int gm0 = tm + wm*(MREP*16) + i*16 + g4*4;
        int b = gm0 >> 10, l0 = gm0 & 1023;
        short4v pk;
#pragma unroll
        for (int r = 0; r < 4; ++r) pk[r] = (short)f2bf(acc[i][j][r] + bia);
        *(short4v*)&out[(((size_t)b * NH_ + h) * HD_ + d) * L_ + l0] = pk;
      }
  } else {
    float* out = (float*)outp;
#pragma unroll
    for (int i = 0; i < MREP; ++i)
#pragma unroll
      for (int j = 0; j < 4; ++j) {
        int c = tn + wn*64 + j*16 + r16;
        float bia = bias[c];
        int gm0 = tm + wm*(MREP*16) + i*16 + g4*4;
        int b = gm0 >> 10, l0 = gm0 & 1023;
        size_t idx = ((size_t)b * C_ + c) * L_ + l0;
        float4 q4 = *(const float4*)&resQ[idx];
        float4 k4 = *(const float4*)&resK[idx];
        float4 o4;
        o4.x = acc[i][j][0] + bia + q4.x + k4.x;
        o4.y = acc[i][j][1] + bia + q4.y + k4.y;
        o4.z = acc[i][j][2] + bia + q4.z + k4.z;
        o4.w = acc[i][j][3] + bia + q4.w + k4.w;
        *(float4*)&out[idx] = o4;
      }
  }
}

// 1D grid, 768 blocks. XCD-grouped.
__global__ __launch_bounds__(256) void k_proj(
    const unsigned short* __restrict__ qf, const unsigned short* __restrict__ kf,
    const unsigned short* __restrict__ Wqb, const unsigned short* __restrict__ Wkb,
    const unsigned short* __restrict__ Wvb,
    const float* __restrict__ bq, const float* __restrict__ bk, const float* __restrict__ bv,
    unsigned short* __restrict__ Qw, unsigned short* __restrict__ Kw,
    unsigned short* __restrict__ VTw) {
  __shared__ unsigned short lA[128 * 64];
  __shared__ unsigned short lB[128 * 64];
  const int bid = blockIdx.x;
  const int xcd = bid & 7;
  const int i_  = bid >> 3;            // 0..95
  const int ml  = i_ / 12;             // 0..7
  const int rem = i_ - ml * 12;        // 0..11
  const int z   = rem >> 2;            // 0..2
  const int n   = rem & 3;             // 0..3
  const int m   = xcd * 8 + ml;        // 0..63
  const unsigned short* A = (z == 0) ? qf : kf;
  const unsigned short* W = (z == 0) ? Wqb : (z == 1) ? Wkb : Wvb;
  const float* bias = (z == 0) ? bq : (z == 1) ? bk : bv;
  void* out = (z == 0) ? (void*)Qw : (z == 1) ? (void*)Kw : (void*)VTw;
  // Q scale folds head-dim scaling AND log2(e) so attn softmax runs in exp2 domain.
  float scale = (z == 0) ? 0.125f * 1.44269504088896f : 1.0f;
  gemm_core<4>(A, W, bias, out, nullptr, nullptr, z, scale, lA, lB, m * 128, n * 128);
}

// 1D grid, 512 blocks (64x128 tile -> 2 blocks/CU for latency hiding).
__global__ __launch_bounds__(256) void k_outproj(
    const unsigned short* __restrict__ O, const unsigned short* __restrict__ Wob,
    const float* __restrict__ bo, float* __restrict__ out,
    const float* __restrict__ query, const float* __restrict__ key) {
  __shared__ unsigned short lA[64 * 64];
  __shared__ unsigned short lB[128 * 64];
  const int bid = blockIdx.x;
  const int xcd = bid & 7;
  const int i_  = bid >> 3;             // 0..63
  const int m   = xcd * 16 + (i_ >> 2); // 0..127
  const int n   = i_ & 3;
  gemm_core<2>(O, Wob, bo, out, query, key, 3, 1.0f, lA, lB, m * 64, n * 128);
}

// ---------------- flash attention ----------------
// Q,K: [B,NH,L,64] bf16 (Q pre-scaled by 0.125*log2e), VT: [B,NH,64,L] bf16.
// 512 blocks (64 bh x 8 q-blocks of 128); 4 waves, 32 q-rows/wave.
// K/V LDS reads amortize over 2x q-rows (per-work LDS floor halves vs QBLK=16);
// two row-groups (i=0,1) give ILP, and the register-P path (no LDS round-trip)
// keeps the per-tile chain short. SWAPPED QK^T with PERMUTED K-rows: MFMA
// (h,c) loads K-row pi = h*32 + (r16>>2)*8 + (r16&3)*2 + c; slot (h,c,g4,r)
// holds key k = h*32 + g4*8 + 2r + c -> exp2 + cvt_pk pack the PV A-operand
// in registers. STATIC-MAX softmax (|s|<=~18 << 127). l on MFMA pipe (ones).
__global__ __launch_bounds__(256, 2) void k_attn(
    const unsigned short* __restrict__ Q, const unsigned short* __restrict__ K,
    const unsigned short* __restrict__ VT, unsigned short* __restrict__ O) {
  __shared__ unsigned short Kt[2][64 * 64];
  __shared__ unsigned short Vt[2][64 * 64];
  const int lane = threadIdx.x & 63;
  const int wid  = threadIdx.x >> 6;
  const int bid  = blockIdx.x;
  const int xcd  = bid & 7;
  const int i_   = bid >> 3;                   // 0..63
  const int bh   = xcd * 8 + (i_ >> 3);        // 0..63, 8 heads per XCD
  const int qb   = i_ & 7;                     // 0..7
  const int qrow0 = qb * 128 + wid * 32;
  const int r16 = lane & 15;
  const int g4  = lane >> 4;
  const size_t base = (size_t)bh * L_ * HD_;
  const unsigned short* Kg = K + base;
  const unsigned short* Vg = VT + base;        // [64 d][1024 l]

  // staging geometry: tile = 64x64 bf16 = 512 slots of 16B; wave stages 128 slots
  const int s0 = wid * 128 + lane;             // slot for i2=0 (i2=1 adds 64)
  const int row0 = s0 >> 3,        ch0 = (s0 & 7) ^ (row0 & 7);
  const int row1 = (s0 + 64) >> 3, ch1 = ((s0 + 64) & 7) ^ (row1 & 7);

#define STAGE_KV(nxt, kt0) { \
    GLD16(Kg + (size_t)((kt0) + row0) * HD_ + ch0 * 8, &Kt[nxt][(wid*128)*8]); \
    GLD16(Kg + (size_t)((kt0) + row1) * HD_ + ch1 * 8, &Kt[nxt][(wid*128+64)*8]); \
    GLD16(Vg + (size_t)row0 * L_ + (kt0) + ch0 * 8, &Vt[nxt][(wid*128)*8]); \
    GLD16(Vg + (size_t)row1 * L_ + (kt0) + ch1 * 8, &Vt[nxt][(wid*128+64)*8]); \
  }

  short8 qv[2][2];
#pragma unroll
  for (int i = 0; i < 2; ++i)
#pragma unroll
    for (int ks = 0; ks < 2; ++ks)
      qv[i][ks] = *(const short8*)(Q + base + (size_t)(qrow0 + i*16 + r16) * HD_ + ks*32 + g4*8);

  short8 vones;
#pragma unroll
  for (int e = 0; e < 8; ++e) vones[e] = (short)0x3F80;   // bf16 1.0

  f32x4 lacc[2];
  f32x4 oacc[2][4];
#pragma unroll
  for (int i = 0; i < 2; ++i) {
    lacc[i] = (f32x4){0.f, 0.f, 0.f, 0.f};
#pragma unroll
    for (int j = 0; j < 4; ++j) oacc[i][j] = (f32x4){0.f, 0.f, 0.f, 0.f};
  }

  STAGE_KV(0, 0);
  __syncthreads();

  int cur = 0;
  for (int t = 0; t < 16; ++t) {
    if (t < 15) STAGE_KV(cur ^ 1, (t + 1) * 64);

    const unsigned short* lK = &Kt[cur][0];
    const unsigned short* lV = &Vt[cur][0];

    f32x4 sc[2][4];
#pragma unroll
    for (int i = 0; i < 2; ++i)
#pragma unroll
      for (int cf = 0; cf < 4; ++cf) sc[i][cf] = (f32x4){0.f, 0.f, 0.f, 0.f};

    __builtin_amdgcn_s_setprio(1);
#pragma unroll
    for (int cf = 0; cf < 4; ++cf) {
      const int h = cf >> 1, c = cf & 1;
      // permuted K-row: A-row r16 <- key row h*32 + (r16>>2)*8 + (r16&3)*2 + c
      const int rr = h*32 + ((r16 >> 2) << 3) + ((r16 & 3) << 1) + c;
      const int s  = ((r16 & 3) << 1) + c;            // rr & 7
      const int rowb = rr * 64;
      short8 kb0 = *(const short8*)&lK[rowb + ((g4) ^ s) * 8];
      short8 kb1 = *(const short8*)&lK[rowb + ((4 + g4) ^ s) * 8];
      sc[0][cf] = MFMA(kb0, qv[0][0], sc[0][cf]);   // swapped: S^T[k, q]
      sc[0][cf] = MFMA(kb1, qv[0][1], sc[0][cf]);
      sc[1][cf] = MFMA(kb0, qv[1][0], sc[1][cf]);
      sc[1][cf] = MFMA(kb1, qv[1][1], sc[1][cf]);
    }
    __builtin_amdgcn_s_setprio(0);

    // p = exp2(s) (static max); pack PV A-fragments in registers per row-group.
    const int swz = r16 & 7;
#pragma unroll
    for (int h = 0; h < 2; ++h) {
      union { unsigned u[4]; short8 s8; } pu0, pu1;
#pragma unroll
      for (int r = 0; r < 4; ++r) {
        pu0.u[r] = cvtpk_bf16(exp2f(sc[0][h*2][r]), exp2f(sc[0][h*2+1][r]));
        pu1.u[r] = cvtpk_bf16(exp2f(sc[1][h*2][r]), exp2f(sc[1][h*2+1][r]));
      }
      short8 pa0 = pu0.s8;
      short8 pa1 = pu1.s8;
      __builtin_amdgcn_s_setprio(1);
      lacc[0] = MFMA(pa0, vones, lacc[0]);
      lacc[1] = MFMA(pa1, vones, lacc[1]);
#pragma unroll
      for (int j = 0; j < 4; ++j) {
        short8 vb = *(const short8*)&lV[(j*16 + r16) * 64 + ((h*4 + g4) ^ swz) * 8];
        oacc[0][j] = MFMA(pa0, vb, oacc[0][j]);
        oacc[1][j] = MFMA(pa1, vb, oacc[1][j]);
      }
      __builtin_amdgcn_s_setprio(0);
    }

    __syncthreads();
    cur ^= 1;
  }

  const int b = bh >> 3, h = bh & 7;
#pragma unroll
  for (int i = 0; i < 2; ++i) {
    float linv[4];
#pragma unroll
    for (int r = 0; r < 4; ++r) linv[r] = 1.0f / lacc[i][r];
#pragma unroll
    for (int j = 0; j < 4; ++j)
#pragma unroll
      for (int r = 0; r < 4; ++r) {
        int row = qrow0 + i*16 + g4*4 + r;
        int col = h*64 + j*16 + r16;
        O[((size_t)b * L_ + row) * C_ + col] = f2bf(oacc[i][j][r] * linv[r]);
      }
  }
#undef STAGE_KV
}

extern "C" void kernel_launch(void* const* d_in, const int* in_sizes, int n_in,
                              void* d_out, int out_size, void* d_ws, size_t ws_size,
                              hipStream_t stream) {
  (void)in_sizes; (void)n_in; (void)out_size; (void)ws_size;
  const float* query = (const float*)d_in[0];
  const float* key   = (const float*)d_in[1];
  const float* Wq = (const float*)d_in[2];
  const float* bq = (const float*)d_in[3];
  const float* Wk = (const float*)d_in[4];
  const float* bk = (const float*)d_in[5];
  const float* Wv = (const float*)d_in[6];
  const float* bv = (const float*)d_in[7];
  const float* Wo = (const float*)d_in[8];
  const float* bo = (const float*)d_in[9];

  char* ws = (char*)d_ws;
  unsigned short* qf  = (unsigned short*)(ws);                  // 8 MB
  unsigned short* kf  = (unsigned short*)(ws + 8388608);        // 8 MB
  unsigned short* Wqb = (unsigned short*)(ws + 16777216);       // 4x 512KB
  unsigned short* Wkb = Wqb + 262144;
  unsigned short* Wvb = Wkb + 262144;
  unsigned short* Wob = Wvb + 262144;
  unsigned short* Qw  = (unsigned short*)(ws + 18874368);       // 8 MB
  unsigned short* Kw  = (unsigned short*)(ws + 27262976);       // 8 MB
  unsigned short* VTw = (unsigned short*)(ws + 35651584);       // 8 MB
  unsigned short* Ow  = (unsigned short*)(ws + 44040192);       // 8 MB

  k_transpose<<<dim3(32, 16, 17), 256, 0, stream>>>(query, key, qf, kf,
                                                    Wq, Wk, Wv, Wo, Wqb);
  k_proj<<<dim3(768), 256, 0, stream>>>(qf, kf, Wqb, Wkb, Wvb, bq, bk, bv, Qw, Kw, VTw);
  k_attn<<<dim3(512), 256, 0, stream>>>(Qw, Kw, VTw, Ow);
  k_outproj<<<dim3(512), 256, 0, stream>>>(Ow, Wob, bo, (float*)d_out, query, key);
}